// Round 1
// baseline (620.988 us; speedup 1.0000x reference)
//
#include <hip/hip_runtime.h>

typedef __bf16 bf16_t;
typedef bf16_t bf16x8 __attribute__((ext_vector_type(8)));
typedef float f32x4 __attribute__((ext_vector_type(4)));

#define BM 128
#define BN 128
#define BK 32

// async global->LDS, 16B per lane. LDS dest = wave-uniform base + lane*16.
#define GLOAD_LDS(gptr, lptr)                                                         \
  __builtin_amdgcn_global_load_lds(                                                   \
      (const __attribute__((address_space(1))) unsigned int*)(gptr),                  \
      (__attribute__((address_space(3))) unsigned int*)(lptr), 16, 0, 0)

// ---------- preprocessing ----------

__global__ void absmax_kernel(const float* __restrict__ p, long n,
                              unsigned* __restrict__ out) {
  __shared__ float sm[4];
  float m = 0.f;
  const long n4 = n >> 2;
  const long stride = (long)gridDim.x * blockDim.x;
  const float4* p4 = (const float4*)p;
  for (long i = blockIdx.x * (long)blockDim.x + threadIdx.x; i < n4; i += stride) {
    float4 v = p4[i];
    m = fmaxf(m, fmaxf(fmaxf(fabsf(v.x), fabsf(v.y)), fmaxf(fabsf(v.z), fabsf(v.w))));
  }
  for (int off = 32; off > 0; off >>= 1)
    m = fmaxf(m, __shfl_down(m, off));
  if ((threadIdx.x & 63) == 0) sm[threadIdx.x >> 6] = m;
  __syncthreads();
  if (threadIdx.x == 0) {
    m = fmaxf(fmaxf(sm[0], sm[1]), fmaxf(sm[2], sm[3]));
    atomicMax(out, __float_as_uint(m));  // nonneg floats: uint bit order == float order
  }
}

// W -> ternary {-1,0,+1} stored as bf16 bits (exact). delta = 0.05*max|W| in fp32,
// bit-matching the jnp reference decision.
__global__ void ternarize_w(const float4* __restrict__ W,
                            const unsigned* __restrict__ dmax,
                            ushort4* __restrict__ T, long n4) {
  long i = blockIdx.x * (long)blockDim.x + threadIdx.x;
  if (i >= n4) return;
  const float delta = 0.05f * __uint_as_float(*dmax);
  float4 w = W[i];
  ushort4 t;
  t.x = w.x > delta ? 0x3F80u : (w.x < -delta ? 0xBF80u : 0u);
  t.y = w.y > delta ? 0x3F80u : (w.y < -delta ? 0xBF80u : 0u);
  t.z = w.z > delta ? 0x3F80u : (w.z < -delta ? 0xBF80u : 0u);
  t.w = w.w > delta ? 0x3F80u : (w.w < -delta ? 0xBF80u : 0u);
  T[i] = t;
}

__global__ void ternarize_b(const float* __restrict__ b,
                            const unsigned* __restrict__ dmax,
                            const float* __restrict__ bscale,
                            float* __restrict__ bt, int n) {
  int i = blockIdx.x * blockDim.x + threadIdx.x;
  if (i >= n) return;
  const float delta = 0.05f * __uint_as_float(*dmax);
  const float s = *bscale;
  float v = b[i];
  bt[i] = v > delta ? s : (v < -delta ? -s : 0.f);
}

__device__ inline unsigned short f2bf_rne(float f) {
  unsigned u = __float_as_uint(f);
  unsigned rounding = 0x7FFFu + ((u >> 16) & 1u);
  return (unsigned short)((u + rounding) >> 16);
}

__global__ void convert_x(const float4* __restrict__ X, ushort4* __restrict__ Y,
                          long n4) {
  long i = blockIdx.x * (long)blockDim.x + threadIdx.x;
  if (i >= n4) return;
  float4 v = X[i];
  ushort4 o;
  o.x = f2bf_rne(v.x);
  o.y = f2bf_rne(v.y);
  o.z = f2bf_rne(v.z);
  o.w = f2bf_rne(v.w);
  Y[i] = o;
}

// ---------- GEMM: C[m,n] = ws * sum_k A[m,k]*B[n,k] + bt[n] ----------
// m97 structure: 128x128 tile, BK=32, 4 waves (2x2), each wave 64x64 via 4x4
// grid of 16x16x32 bf16 MFMAs. global_load_lds width=16 staging, 2-barrier loop.
__global__ __launch_bounds__(256) void gemm_tern(
    const bf16_t* __restrict__ A,   // [M,K] bf16 x
    const bf16_t* __restrict__ B,   // [N,K] bf16 ternary {-1,0,1}
    const float* __restrict__ bt,   // [N]
    const float* __restrict__ wsc,  // scalar
    float* __restrict__ C,          // [M,N] fp32
    int M, int N, int K) {
  __shared__ __align__(16) bf16_t sA[BM * BK];
  __shared__ __align__(16) bf16_t sB[BN * BK];

  const int tid = threadIdx.x;
  const int wave = tid >> 6;
  const int lane = tid & 63;
  const int wm = wave >> 1, wn = wave & 1;
  const int quad = lane >> 4;  // 0..3
  const int l16 = lane & 15;

  const int bm0 = blockIdx.y * BM;
  const int bn0 = blockIdx.x * BN;

  // staging: thread t loads row t/4 (+64 for step 1), 8 bf16 at col (t%4)*8.
  // LDS dest for wave w step s: base sX + (s*64 + w*16)*BK, HW adds lane*16B.
  const int srow = tid >> 2;
  const int scol = (tid & 3) * 8;

  const bf16_t* gA0 = A + (size_t)(bm0 + srow) * K + scol;
  const bf16_t* gA1 = A + (size_t)(bm0 + 64 + srow) * K + scol;
  const bf16_t* gB0 = B + (size_t)(bn0 + srow) * K + scol;
  const bf16_t* gB1 = B + (size_t)(bn0 + 64 + srow) * K + scol;

  bf16_t* lA0 = sA + (wave * 16) * BK;
  bf16_t* lA1 = sA + (64 + wave * 16) * BK;
  bf16_t* lB0 = sB + (wave * 16) * BK;
  bf16_t* lB1 = sB + (64 + wave * 16) * BK;

  // fragment bases: row = (w?*64 + tile*16 + l16), 8 contiguous k at quad*8
  const bf16x8* fA = (const bf16x8*)(sA + ((wm * 64 + l16) * BK) + quad * 8);
  const bf16x8* fB = (const bf16x8*)(sB + ((wn * 64 + l16) * BK) + quad * 8);
  // tile stride: 16 rows * 32 bf16 = 512 bf16 = 64 bf16x8

  f32x4 acc[4][4] = {};

  for (int k0 = 0; k0 < K; k0 += BK) {
    GLOAD_LDS(gA0, lA0);
    GLOAD_LDS(gA1, lA1);
    GLOAD_LDS(gB0, lB0);
    GLOAD_LDS(gB1, lB1);
    gA0 += BK; gA1 += BK; gB0 += BK; gB1 += BK;
    __syncthreads();  // compiler drains vmcnt(0) before s_barrier

    bf16x8 af[4], bfr[4];
#pragma unroll
    for (int i = 0; i < 4; ++i) af[i] = fA[i * 64];
#pragma unroll
    for (int i = 0; i < 4; ++i) bfr[i] = fB[i * 64];
#pragma unroll
    for (int mt = 0; mt < 4; ++mt)
#pragma unroll
      for (int nt = 0; nt < 4; ++nt)
        acc[mt][nt] = __builtin_amdgcn_mfma_f32_16x16x32_bf16(
            af[mt], bfr[nt], acc[mt][nt], 0, 0, 0);
    __syncthreads();  // all waves done reading before next stage overwrites
  }

  // epilogue: D layout col=lane&15, row=quad*4+reg
  const float ws = *wsc;
#pragma unroll
  for (int mt = 0; mt < 4; ++mt) {
    const int row = bm0 + wm * 64 + mt * 16 + quad * 4;
#pragma unroll
    for (int nt = 0; nt < 4; ++nt) {
      const int col = bn0 + wn * 64 + nt * 16 + l16;
      const float bias = bt[col];
      f32x4 a = acc[mt][nt];
#pragma unroll
      for (int r = 0; r < 4; ++r)
        C[(size_t)(row + r) * N + col] = ws * a[r] + bias;
    }
  }
}

// ---------- launch ----------

extern "C" void kernel_launch(void* const* d_in, const int* in_sizes, int n_in,
                              void* d_out, int out_size, void* d_ws, size_t ws_size,
                              hipStream_t stream) {
  const float* x = (const float*)d_in[0];
  const float* W = (const float*)d_in[1];
  const float* w_scale = (const float*)d_in[2];
  const float* b = (const float*)d_in[3];
  const float* b_scale = (const float*)d_in[4];
  float* out = (float*)d_out;

  const int K = 4096;                      // D_IN
  const int N = in_sizes[3];               // D_OUT = 4096
  const int M = in_sizes[0] / K;           // B*S = 8192

  // workspace layout
  char* ws = (char*)d_ws;
  bf16_t* xb = (bf16_t*)ws;                                  // M*K bf16
  bf16_t* Tw = (bf16_t*)(ws + (size_t)M * K * 2);            // N*K bf16
  float* bt = (float*)(ws + (size_t)M * K * 2 + (size_t)N * K * 2);  // N fp32
  unsigned* mx = (unsigned*)((char*)bt + (size_t)N * 4);     // [0]=max|W|,[1]=max|b|

  hipMemsetAsync(mx, 0, 8, stream);
  absmax_kernel<<<1024, 256, 0, stream>>>(W, (long)N * K, mx);
  absmax_kernel<<<8, 256, 0, stream>>>(b, (long)N, mx + 1);

  {
    long n4 = (long)N * K / 4;
    ternarize_w<<<(n4 + 255) / 256, 256, 0, stream>>>((const float4*)W, mx,
                                                      (ushort4*)Tw, n4);
  }
  ternarize_b<<<(N + 255) / 256, 256, 0, stream>>>(b, mx + 1, b_scale, bt, N);
  {
    long n4 = (long)M * K / 4;
    convert_x<<<(n4 + 255) / 256, 256, 0, stream>>>((const float4*)x,
                                                    (ushort4*)xb, n4);
  }

  dim3 grid(N / BN, M / BM);
  gemm_tern<<<grid, 256, 0, stream>>>(xb, Tw, bt, w_scale, out, M, N, K);
}

// Round 2
// 601.731 us; speedup vs baseline: 1.0320x; 1.0320x over previous
//
#include <hip/hip_runtime.h>

typedef __bf16 bf16_t;
typedef bf16_t bf16x8 __attribute__((ext_vector_type(8)));
typedef float f32x4 __attribute__((ext_vector_type(4)));

#define BM 128
#define BN 128
#define BK 32

// async global->LDS, 16B per lane. LDS dest = wave-uniform base + lane*16.
#define GLOAD_LDS(gptr, lptr)                                                         \
  __builtin_amdgcn_global_load_lds(                                                   \
      (const __attribute__((address_space(1))) unsigned int*)(gptr),                  \
      (__attribute__((address_space(3))) unsigned int*)(lptr), 16, 0, 0)

// ---------- preprocessing ----------

// One dispatch: blocks [0, grid-2] reduce max|W|, last block reduces max|b|.
__global__ void absmax2_kernel(const float4* __restrict__ W4, long nW4,
                               const float4* __restrict__ b4, int nb4,
                               unsigned* __restrict__ mx) {
  __shared__ float sm[4];
  float m = 0.f;
  const bool isB = (blockIdx.x == gridDim.x - 1);
  if (!isB) {
    const long stride = (long)(gridDim.x - 1) * blockDim.x;
    for (long i = blockIdx.x * (long)blockDim.x + threadIdx.x; i < nW4; i += stride) {
      float4 v = W4[i];
      m = fmaxf(m, fmaxf(fmaxf(fabsf(v.x), fabsf(v.y)), fmaxf(fabsf(v.z), fabsf(v.w))));
    }
  } else {
    for (int i = threadIdx.x; i < nb4; i += blockDim.x) {
      float4 v = b4[i];
      m = fmaxf(m, fmaxf(fmaxf(fabsf(v.x), fabsf(v.y)), fmaxf(fabsf(v.z), fabsf(v.w))));
    }
  }
  for (int off = 32; off > 0; off >>= 1)
    m = fmaxf(m, __shfl_down(m, off));
  if ((threadIdx.x & 63) == 0) sm[threadIdx.x >> 6] = m;
  __syncthreads();
  if (threadIdx.x == 0) {
    m = fmaxf(fmaxf(sm[0], sm[1]), fmaxf(sm[2], sm[3]));
    atomicMax(mx + (isB ? 1 : 0), __float_as_uint(m));  // nonneg: uint order == float order
  }
}

__device__ inline unsigned short f2bf_rne(float f) {
  unsigned u = __float_as_uint(f);
  unsigned rounding = 0x7FFFu + ((u >> 16) & 1u);
  return (unsigned short)((u + rounding) >> 16);
}

// Fused: ternarize W -> bf16{-1,0,1}, convert x -> bf16, ternarize b -> fp32.
__global__ void prep_kernel(const float4* __restrict__ W4, long nW4,
                            const float4* __restrict__ X4, long nX4,
                            const float4* __restrict__ b4, int nb4,
                            const unsigned* __restrict__ mx,
                            const float* __restrict__ bscale,
                            ushort4* __restrict__ Tw, ushort4* __restrict__ Xb,
                            float4* __restrict__ bt) {
  if (blockIdx.x == gridDim.x - 1) {  // bias block
    const float delta = 0.05f * __uint_as_float(mx[1]);
    const float s = *bscale;
    for (int i = threadIdx.x; i < nb4; i += blockDim.x) {
      float4 v = b4[i];
      float4 o;
      o.x = v.x > delta ? s : (v.x < -delta ? -s : 0.f);
      o.y = v.y > delta ? s : (v.y < -delta ? -s : 0.f);
      o.z = v.z > delta ? s : (v.z < -delta ? -s : 0.f);
      o.w = v.w > delta ? s : (v.w < -delta ? -s : 0.f);
      bt[i] = o;
    }
    return;
  }
  long i = blockIdx.x * (long)blockDim.x + threadIdx.x;
  if (i < nW4) {
    const float delta = 0.05f * __uint_as_float(mx[0]);
    float4 w = W4[i];
    ushort4 t;
    t.x = w.x > delta ? 0x3F80u : (w.x < -delta ? 0xBF80u : 0u);
    t.y = w.y > delta ? 0x3F80u : (w.y < -delta ? 0xBF80u : 0u);
    t.z = w.z > delta ? 0x3F80u : (w.z < -delta ? 0xBF80u : 0u);
    t.w = w.w > delta ? 0x3F80u : (w.w < -delta ? 0xBF80u : 0u);
    Tw[i] = t;
  } else {
    long j = i - nW4;
    if (j < nX4) {
      float4 v = X4[j];
      ushort4 o;
      o.x = f2bf_rne(v.x);
      o.y = f2bf_rne(v.y);
      o.z = f2bf_rne(v.z);
      o.w = f2bf_rne(v.w);
      Xb[j] = o;
    }
  }
}

// ---------- GEMM: C[m,n] = ws * sum_k A[m,k]*B[n,k] + bt[n] ----------
// m97 structure: 128x128 tile, BK=32, 4 waves (2x2), each wave 64x64 via 4x4
// grid of 16x16x32 bf16 MFMAs. global_load_lds width=16 staging, 2-barrier loop.
// LDS layout XOR-swizzled: chunk c (16B) of row r lives at chunk c ^ ((r>>1)&3).
// Realized on the staging side by permuting lane->global-chunk (LDS dest of
// global_load_lds is fixed at base+lane*16B). Kills the 8-way ds_read_b128
// bank aliasing of the naive layout (each 4-bank group now 2 lanes = free).
__global__ __launch_bounds__(256) void gemm_tern(
    const bf16_t* __restrict__ A,   // [M,K] bf16 x
    const bf16_t* __restrict__ B,   // [N,K] bf16 ternary {-1,0,1}
    const float* __restrict__ bt,   // [N]
    const float* __restrict__ wsc,  // scalar
    float* __restrict__ C,          // [M,N] fp32
    int M, int N, int K) {
  __shared__ __align__(16) bf16_t sA[BM * BK];
  __shared__ __align__(16) bf16_t sB[BN * BK];

  const int tid = threadIdx.x;
  const int wave = tid >> 6;
  const int lane = tid & 63;
  const int wm = wave >> 1, wn = wave & 1;
  const int quad = lane >> 4;  // 0..3
  const int l16 = lane & 15;

  const int bm0 = blockIdx.y * BM;
  const int bn0 = blockIdx.x * BN;

  // staging: thread t covers row t/4, LDS chunk t%4. XOR swizzle: global chunk
  // fetched = (t&3) ^ ((row>>1)&3) = (t&3) ^ ((t>>3)&3).
  const int srow = tid >> 2;
  const int scol = ((tid & 3) ^ ((tid >> 3) & 3)) * 8;

  const bf16_t* gA0 = A + (size_t)(bm0 + srow) * K + scol;
  const bf16_t* gA1 = A + (size_t)(bm0 + 64 + srow) * K + scol;
  const bf16_t* gB0 = B + (size_t)(bn0 + srow) * K + scol;
  const bf16_t* gB1 = B + (size_t)(bn0 + 64 + srow) * K + scol;

  bf16_t* lA0 = sA + (wave * 16) * BK;
  bf16_t* lA1 = sA + (64 + wave * 16) * BK;
  bf16_t* lB0 = sB + (wave * 16) * BK;
  bf16_t* lB1 = sB + (64 + wave * 16) * BK;

  // fragment bases: row = wm*64 + mt*16 + l16; k-chunk quad stored at
  // chunk quad ^ ((l16>>1)&3)  (row>>1 & 3 == l16>>1 & 3: tile offsets are *16)
  const int kchunk = quad ^ ((l16 >> 1) & 3);
  const bf16x8* fA = (const bf16x8*)(sA + ((wm * 64 + l16) * BK) + kchunk * 8);
  const bf16x8* fB = (const bf16x8*)(sB + ((wn * 64 + l16) * BK) + kchunk * 8);
  // tile stride: 16 rows * 32 bf16 = 512 bf16 = 64 bf16x8

  f32x4 acc[4][4] = {};

  for (int k0 = 0; k0 < K; k0 += BK) {
    GLOAD_LDS(gA0, lA0);
    GLOAD_LDS(gA1, lA1);
    GLOAD_LDS(gB0, lB0);
    GLOAD_LDS(gB1, lB1);
    gA0 += BK; gA1 += BK; gB0 += BK; gB1 += BK;
    __syncthreads();  // compiler drains vmcnt(0) before s_barrier

    bf16x8 af[4], bfr[4];
#pragma unroll
    for (int i = 0; i < 4; ++i) af[i] = fA[i * 64];
#pragma unroll
    for (int i = 0; i < 4; ++i) bfr[i] = fB[i * 64];
#pragma unroll
    for (int mt = 0; mt < 4; ++mt)
#pragma unroll
      for (int nt = 0; nt < 4; ++nt)
        acc[mt][nt] = __builtin_amdgcn_mfma_f32_16x16x32_bf16(
            af[mt], bfr[nt], acc[mt][nt], 0, 0, 0);
    __syncthreads();  // all waves done reading before next stage overwrites
  }

  // epilogue: D layout col=lane&15, row=quad*4+reg
  const float ws = *wsc;
#pragma unroll
  for (int mt = 0; mt < 4; ++mt) {
    const int row = bm0 + wm * 64 + mt * 16 + quad * 4;
#pragma unroll
    for (int nt = 0; nt < 4; ++nt) {
      const int col = bn0 + wn * 64 + nt * 16 + l16;
      const float bias = bt[col];
      f32x4 a = acc[mt][nt];
#pragma unroll
      for (int r = 0; r < 4; ++r)
        C[(size_t)(row + r) * N + col] = ws * a[r] + bias;
    }
  }
}

// ---------- launch ----------

extern "C" void kernel_launch(void* const* d_in, const int* in_sizes, int n_in,
                              void* d_out, int out_size, void* d_ws, size_t ws_size,
                              hipStream_t stream) {
  const float* x = (const float*)d_in[0];
  const float* W = (const float*)d_in[1];
  const float* w_scale = (const float*)d_in[2];
  const float* b = (const float*)d_in[3];
  const float* b_scale = (const float*)d_in[4];
  float* out = (float*)d_out;

  const int K = 4096;                      // D_IN
  const int N = in_sizes[3];               // D_OUT = 4096
  const int M = in_sizes[0] / K;           // B*S = 8192

  // workspace layout
  char* ws = (char*)d_ws;
  bf16_t* xb = (bf16_t*)ws;                                  // M*K bf16
  bf16_t* Tw = (bf16_t*)(ws + (size_t)M * K * 2);            // N*K bf16
  float* bt = (float*)(ws + (size_t)M * K * 2 + (size_t)N * K * 2);  // N fp32
  unsigned* mx = (unsigned*)((char*)bt + (size_t)N * 4);     // [0]=max|W|,[1]=max|b|

  hipMemsetAsync(mx, 0, 8, stream);

  const long nW4 = (long)N * K / 4;
  const long nX4 = (long)M * K / 4;
  const int nb4 = N / 4;

  absmax2_kernel<<<1025, 256, 0, stream>>>((const float4*)W, nW4,
                                           (const float4*)b, nb4, mx);

  long ntot = nW4 + nX4;
  int grid = (int)((ntot + 255) / 256) + 1;
  prep_kernel<<<grid, 256, 0, stream>>>((const float4*)W, nW4, (const float4*)x,
                                        nX4, (const float4*)b, nb4, mx, b_scale,
                                        (ushort4*)Tw, (ushort4*)xb, (float4*)bt);

  dim3 gg(N / BN, M / BM);
  gemm_tern<<<gg, 256, 0, stream>>>(xb, Tw, bt, w_scale, out, M, N, K);
}

// Round 3
// 484.298 us; speedup vs baseline: 1.2822x; 1.2425x over previous
//
#include <hip/hip_runtime.h>

typedef int v4i __attribute__((ext_vector_type(4)));

#define BM 128
#define BN 128
#define BK 64  // i8: 64 bytes per LDS row — byte-identical geometry to bf16/BK=32

// async global->LDS, 16B per lane. LDS dest = wave-uniform base + lane*16.
#define GLOAD_LDS(gptr, lptr)                                                         \
  __builtin_amdgcn_global_load_lds(                                                   \
      (const __attribute__((address_space(1))) unsigned int*)(gptr),                  \
      (__attribute__((address_space(3))) unsigned int*)(lptr), 16, 0, 0)

// ---------- preprocessing ----------

// One dispatch: blocks [0, grid-2] reduce max|W|, last block reduces max|b|.
__global__ void absmax2_kernel(const float4* __restrict__ W4, long nW4,
                               const float4* __restrict__ b4, int nb4,
                               unsigned* __restrict__ mx) {
  __shared__ float sm[4];
  float m = 0.f;
  const bool isB = (blockIdx.x == gridDim.x - 1);
  if (!isB) {
    const long stride = (long)(gridDim.x - 1) * blockDim.x;
    for (long i = blockIdx.x * (long)blockDim.x + threadIdx.x; i < nW4; i += stride) {
      float4 v = W4[i];
      m = fmaxf(m, fmaxf(fmaxf(fabsf(v.x), fabsf(v.y)), fmaxf(fabsf(v.z), fabsf(v.w))));
    }
  } else {
    for (int i = threadIdx.x; i < nb4; i += blockDim.x) {
      float4 v = b4[i];
      m = fmaxf(m, fmaxf(fmaxf(fabsf(v.x), fabsf(v.y)), fmaxf(fabsf(v.z), fabsf(v.w))));
    }
  }
  for (int off = 32; off > 0; off >>= 1)
    m = fmaxf(m, __shfl_down(m, off));
  if ((threadIdx.x & 63) == 0) sm[threadIdx.x >> 6] = m;
  __syncthreads();
  if (threadIdx.x == 0) {
    m = fmaxf(fmaxf(sm[0], sm[1]), fmaxf(sm[2], sm[3]));
    atomicMax(mx + (isB ? 1 : 0), __float_as_uint(m));  // nonneg: uint order == float order
  }
}

// Per-row int8 quantization of x: one block per row (K=4096, 256 threads x 16 vals).
// s_row = rowmax/127; q = clamp(rint(x*127/rowmax)). Exact i32 accumulation later
// makes this the ONLY error source in the whole pipeline.
__global__ void xquant_kernel(const float4* __restrict__ X4,
                              signed char* __restrict__ Q,
                              float* __restrict__ sx, int K) {
  __shared__ float sm[4];
  const int row = blockIdx.x;
  const int tid = threadIdx.x;
  const float4* xr = X4 + (size_t)row * (K / 4);
  float4 v[4];  // assumes K == 4096: 256 threads * 4 float4 = 1024 float4
  float m = 0.f;
#pragma unroll
  for (int i = 0; i < 4; ++i) {
    v[i] = xr[tid * 4 + i];
    m = fmaxf(m, fmaxf(fmaxf(fabsf(v[i].x), fabsf(v[i].y)),
                       fmaxf(fabsf(v[i].z), fabsf(v[i].w))));
  }
  for (int off = 32; off > 0; off >>= 1) m = fmaxf(m, __shfl_down(m, off));
  if ((tid & 63) == 0) sm[tid >> 6] = m;
  __syncthreads();
  const float total = fmaxf(fmaxf(sm[0], sm[1]), fmaxf(sm[2], sm[3]));
  const float inv = 127.f / total;
  int wds[4];
#pragma unroll
  for (int i = 0; i < 4; ++i) {
    const float* f = (const float*)&v[i];
    int b[4];
#pragma unroll
    for (int j = 0; j < 4; ++j) {
      float r = rintf(f[j] * inv);
      r = fmaxf(-127.f, fminf(127.f, r));
      b[j] = ((int)r) & 255;
    }
    wds[i] = b[0] | (b[1] << 8) | (b[2] << 16) | (b[3] << 24);
  }
  v4i* out = (v4i*)(Q + (size_t)row * K);
  v4i o = {wds[0], wds[1], wds[2], wds[3]};
  out[tid] = o;
  if (tid == 0) sx[row] = total * (1.f / 127.f);
}

// Fused: ternarize W -> i8{-1,0,1} (16 vals/thread), ternarize b -> fp32 (last block).
__global__ void prep_w_kernel(const float4* __restrict__ W4, long nW16,
                              const float4* __restrict__ b4, int nb4,
                              const unsigned* __restrict__ mx,
                              const float* __restrict__ bscale,
                              v4i* __restrict__ Tw, float4* __restrict__ bt) {
  if (blockIdx.x == gridDim.x - 1) {  // bias block
    const float delta = 0.05f * __uint_as_float(mx[1]);
    const float s = *bscale;
    for (int i = threadIdx.x; i < nb4; i += blockDim.x) {
      float4 v = b4[i];
      float4 o;
      o.x = v.x > delta ? s : (v.x < -delta ? -s : 0.f);
      o.y = v.y > delta ? s : (v.y < -delta ? -s : 0.f);
      o.z = v.z > delta ? s : (v.z < -delta ? -s : 0.f);
      o.w = v.w > delta ? s : (v.w < -delta ? -s : 0.f);
      bt[i] = o;
    }
    return;
  }
  long i = blockIdx.x * (long)blockDim.x + threadIdx.x;
  if (i >= nW16) return;
  const float delta = 0.05f * __uint_as_float(mx[0]);
  int wds[4];
#pragma unroll
  for (int u = 0; u < 4; ++u) {
    float4 w = W4[i * 4 + u];
    int b0 = w.x > delta ? 1 : (w.x < -delta ? 0xFF : 0);
    int b1 = w.y > delta ? 1 : (w.y < -delta ? 0xFF : 0);
    int b2 = w.z > delta ? 1 : (w.z < -delta ? 0xFF : 0);
    int b3 = w.w > delta ? 1 : (w.w < -delta ? 0xFF : 0);
    wds[u] = b0 | (b1 << 8) | (b2 << 16) | (b3 << 24);
  }
  v4i o = {wds[0], wds[1], wds[2], wds[3]};
  Tw[i] = o;
}

// ---------- GEMM: C[m,n] = ws*sx[m]*(sum_k Aq[m,k]*T[n,k]) + bt[n], exact i32 acc ----
// m97 structure, i8 edition: 128x128 tile, BK=64, 4 waves (2x2), each wave 64x64 via
// 4x4 grid of 16x16x64 i8 MFMAs. Same 8KB-per-matrix LDS geometry + XOR swizzle as
// the bf16 version (64B rows), but each iteration covers K=64: half the iterations,
// half the staged bytes, half the barriers, 2x MFMA rate.
__global__ __launch_bounds__(256) void gemm_tern_i8(
    const signed char* __restrict__ A,   // [M,K] i8 quantized x
    const signed char* __restrict__ B,   // [N,K] i8 ternary {-1,0,1}
    const float* __restrict__ sx,        // [M] per-row x scale
    const float* __restrict__ bt,        // [N]
    const float* __restrict__ wsc,       // scalar
    float* __restrict__ C,               // [M,N] fp32
    int M, int N, int K) {
  __shared__ __align__(16) signed char sA[BM * BK];  // 8 KB
  __shared__ __align__(16) signed char sB[BN * BK];  // 8 KB

  const int tid = threadIdx.x;
  const int wave = tid >> 6;
  const int lane = tid & 63;
  const int wm = wave >> 1, wn = wave & 1;
  const int quad = lane >> 4;  // 0..3
  const int l16 = lane & 15;

  const int bm0 = blockIdx.y * BM;
  const int bn0 = blockIdx.x * BN;

  // staging: thread t covers row t/4, LDS chunk t%4 (16B chunks). XOR swizzle:
  // global chunk fetched = (t&3) ^ ((row>>1)&3) = (t&3) ^ ((t>>3)&3).
  const int srow = tid >> 2;
  const int scol = ((tid & 3) ^ ((tid >> 3) & 3)) * 16;  // bytes

  const signed char* gA0 = A + (size_t)(bm0 + srow) * K + scol;
  const signed char* gA1 = A + (size_t)(bm0 + 64 + srow) * K + scol;
  const signed char* gB0 = B + (size_t)(bn0 + srow) * K + scol;
  const signed char* gB1 = B + (size_t)(bn0 + 64 + srow) * K + scol;

  signed char* lA0 = sA + (wave * 16) * BK;
  signed char* lA1 = sA + (64 + wave * 16) * BK;
  signed char* lB0 = sB + (wave * 16) * BK;
  signed char* lB1 = sB + (64 + wave * 16) * BK;

  // fragment: row = wm*64 + mt*16 + l16, 16 contiguous k-bytes at chunk
  // quad ^ ((l16>>1)&3) (swizzled). One ds_read_b128, 2-way banks = free.
  const int kchunk = quad ^ ((l16 >> 1) & 3);
  const v4i* fA = (const v4i*)(sA + (wm * 64 + l16) * BK + kchunk * 16);
  const v4i* fB = (const v4i*)(sB + (wn * 64 + l16) * BK + kchunk * 16);
  // mt tile stride: 16 rows * 64 B = 1024 B = 64 v4i

  v4i acc[4][4] = {};

  for (int k0 = 0; k0 < K; k0 += BK) {
    GLOAD_LDS(gA0, lA0);
    GLOAD_LDS(gA1, lA1);
    GLOAD_LDS(gB0, lB0);
    GLOAD_LDS(gB1, lB1);
    gA0 += BK; gA1 += BK; gB0 += BK; gB1 += BK;
    __syncthreads();  // drains vmcnt(0) before s_barrier

    v4i af[4], bfr[4];
#pragma unroll
    for (int i = 0; i < 4; ++i) af[i] = fA[i * 64];
#pragma unroll
    for (int i = 0; i < 4; ++i) bfr[i] = fB[i * 64];
#pragma unroll
    for (int mt = 0; mt < 4; ++mt)
#pragma unroll
      for (int nt = 0; nt < 4; ++nt)
        acc[mt][nt] = __builtin_amdgcn_mfma_i32_16x16x64_i8(
            af[mt], bfr[nt], acc[mt][nt], 0, 0, 0);
    __syncthreads();  // all waves done reading before next stage overwrites
  }

  // epilogue: D layout col=lane&15, row=quad*4+reg (shape-determined, dtype-indep)
  const float ws = *wsc;
#pragma unroll
  for (int mt = 0; mt < 4; ++mt) {
    const int row = bm0 + wm * 64 + mt * 16 + quad * 4;
    float sc[4];
#pragma unroll
    for (int r = 0; r < 4; ++r) sc[r] = ws * sx[row + r];
#pragma unroll
    for (int nt = 0; nt < 4; ++nt) {
      const int col = bn0 + wn * 64 + nt * 16 + l16;
      const float bias = bt[col];
#pragma unroll
      for (int r = 0; r < 4; ++r)
        C[(size_t)(row + r) * N + col] = sc[r] * (float)acc[mt][nt][r] + bias;
    }
  }
}

// ---------- launch ----------

extern "C" void kernel_launch(void* const* d_in, const int* in_sizes, int n_in,
                              void* d_out, int out_size, void* d_ws, size_t ws_size,
                              hipStream_t stream) {
  const float* x = (const float*)d_in[0];
  const float* W = (const float*)d_in[1];
  const float* w_scale = (const float*)d_in[2];
  const float* b = (const float*)d_in[3];
  const float* b_scale = (const float*)d_in[4];
  float* out = (float*)d_out;

  const int K = 4096;             // D_IN
  const int N = in_sizes[3];      // D_OUT = 4096
  const int M = in_sizes[0] / K;  // B*S = 8192

  // workspace layout
  char* ws = (char*)d_ws;
  signed char* xb = (signed char*)ws;                        // M*K i8 (32 MB)
  signed char* Tw = (signed char*)(ws + (size_t)M * K);      // N*K i8 (16 MB)
  float* bt = (float*)(ws + (size_t)M * K + (size_t)N * K);  // N fp32
  float* sx = bt + N;                                        // M fp32
  unsigned* mx = (unsigned*)(sx + M);                        // [0]=max|W|,[1]=max|b|

  hipMemsetAsync(mx, 0, 8, stream);

  const long nW4 = (long)N * K / 4;
  const int nb4 = N / 4;

  absmax2_kernel<<<1025, 256, 0, stream>>>((const float4*)W, nW4,
                                           (const float4*)b, nb4, mx);

  xquant_kernel<<<M, 256, 0, stream>>>((const float4*)x, xb, sx, K);

  const long nW16 = (long)N * K / 16;
  int gridW = (int)((nW16 + 255) / 256) + 1;
  prep_w_kernel<<<gridW, 256, 0, stream>>>((const float4*)W, nW16,
                                           (const float4*)b, nb4, mx, b_scale,
                                           (v4i*)Tw, (float4*)bt);

  dim3 gg(N / BN, M / BM);
  gemm_tern_i8<<<gg, 256, 0, stream>>>(xb, Tw, sx, bt, w_scale, out, M, N, K);
}